// Round 1
// baseline (605.460 us; speedup 1.0000x reference)
//
#include <hip/hip_runtime.h>
#include <math.h>

#define D_MODEL 768
#define HEADS   8
#define HDIM    96
#define SEQ     49
#define KQ      100
#define NB      128
#define FDIM    2048
#define FFD     2048
#define GRP     10
#define NCLS    1000

typedef unsigned short ushort_t;
typedef unsigned int uint_t;
typedef __attribute__((ext_vector_type(8))) short short8;
typedef __attribute__((ext_vector_type(4))) float f32x4;

// ---------------------------------------------------------------------------
// bf16 helpers (RNE rounding)
// ---------------------------------------------------------------------------
__device__ __forceinline__ float bf2f(ushort_t u) {
    uint_t x = ((uint_t)u) << 16;
    return __uint_as_float(x);
}
__device__ __forceinline__ ushort_t f2bf(float f) {
    uint_t x = __float_as_uint(f);
    x += 0x7fffu + ((x >> 16) & 1u);
    return (ushort_t)(x >> 16);
}

// async global->LDS, 16 bytes per lane (lds dest = wave-uniform base + lane*16)
__device__ __forceinline__ void gld_lds16(const void* g, void* l) {
    __builtin_amdgcn_global_load_lds(
        (const __attribute__((address_space(1))) unsigned int*)g,
        (__attribute__((address_space(3))) unsigned int*)l, 16, 0, 0);
}

// ---------------------------------------------------------------------------
// bf16 MFMA GEMM, BK=64, single-buffer (R8 structure), LDS XOR-swizzle
// (conflict-free, R6), XCD-aware block swizzle.  Kept for embed (75 blocks at
// 256^2 would starve CUs) and the tiny qb GEMM.
// A: [M][K] bf16 row-major.  Bt: [N][K] bf16 row-major.
// Block tile: (MT*32) x 128, 256 thr = 4 waves (2x2), wave = (MT*16)x64.
// ---------------------------------------------------------------------------
template <int MT>
__global__ __launch_bounds__(256, 4) void gemm_bf16(
    const ushort_t* __restrict__ A, const ushort_t* __restrict__ Bt,
    const float* __restrict__ bias, const float* __restrict__ bias2,
    ushort_t* __restrict__ C, ushort_t* __restrict__ C2,
    int M, int N, int K, int nsplit, int relu, float scale,
    const ushort_t* __restrict__ resid, int rmode)
{
    constexpr int BM  = MT * 32;        // block rows
    constexpr int ACH = MT * 4;         // A chunks (8 rows x 64k each)
    constexpr int NCH = (ACH + 16) / 4; // staging chunks per wave

    __shared__ ushort_t As[BM * 64];
    __shared__ ushort_t Bs[128 * 64];

    const int tid  = threadIdx.x;
    const int w    = tid >> 6;
    const int lane = tid & 63;
    const int quad = lane >> 4;
    const int l16  = lane & 15;

    // ---- XCD-aware remap of (by,bx) -> (r,c) ----
    const int nx = gridDim.x, NY = gridDim.y;
    const int bid = blockIdx.y * nx + blockIdx.x;
    const int NYmain = NY & ~7;
    const int Tmain = NYmain * nx;
    int r, c;
    if (bid < Tmain) {
        const int grp = bid / (8 * nx);
        const int rem = bid - grp * 8 * nx;
        r = grp * 8 + (rem & 7);
        c = rem >> 3;
    } else {
        const int rem = bid - Tmain;
        r = NYmain + rem / nx;
        c = rem - (rem / nx) * nx;
    }
    const int rowBase = r * BM;
    const int nBase   = c * 128;
    const int wr = (w >> 1) * (MT * 16);
    const int wc = (w & 1) * 64;

    const float* biasb;
    ushort_t* Cb;
    int coff, ldcb;
    if (nBase < nsplit) { biasb = bias;  Cb = C;  coff = 0;      ldcb = nsplit; }
    else                { biasb = bias2; Cb = C2; coff = nsplit; ldcb = N - nsplit; }

    f32x4 acc[MT][4];
#pragma unroll
    for (int i = 0; i < MT; i++)
#pragma unroll
        for (int j = 0; j < 4; j++) acc[i][j] = (f32x4){0.f, 0.f, 0.f, 0.f};

    const int lrow = lane >> 3;
    const int ksub = ((lane & 7) ^ ((lane >> 3) & 7)) * 8;

    const ushort_t* gp[NCH];
    ushort_t* lp[NCH];
#pragma unroll
    for (int i = 0; i < NCH; i++) {
        int ch = w + 4 * i;
        if (ch < ACH) {
            int rr = min(rowBase + ch * 8 + lrow, M - 1);
            gp[i] = A + (size_t)rr * K + ksub;
            lp[i] = As + ch * 512 + lane * 8;
        } else {
            int cb = ch - ACH;
            int rr = nBase + cb * 8 + lrow;
            gp[i] = Bt + (size_t)rr * K + ksub;
            lp[i] = Bs + cb * 512 + lane * 8;
        }
    }

    const int swl = l16 & 7;

    for (int k0 = 0; k0 < K; k0 += 64) {
#pragma unroll
        for (int i = 0; i < NCH; i++) gld_lds16(gp[i] + k0, lp[i]);
        __syncthreads();

#pragma unroll
        for (int s = 0; s < 2; s++) {
            const int ks = ((4 * s + quad) ^ swl) * 8;
            short8 af[MT], bfr[4];
#pragma unroll
            for (int mt = 0; mt < MT; mt++)
                af[mt] = *(const short8*)(As + (wr + mt * 16 + l16) * 64 + ks);
#pragma unroll
            for (int nt = 0; nt < 4; nt++)
                bfr[nt] = *(const short8*)(Bs + (wc + nt * 16 + l16) * 64 + ks);
#pragma unroll
            for (int mt = 0; mt < MT; mt++)
#pragma unroll
                for (int nt = 0; nt < 4; nt++)
                    acc[mt][nt] = __builtin_amdgcn_mfma_f32_16x16x32_bf16(
                        af[mt], bfr[nt], acc[mt][nt], 0, 0, 0);
        }
        __syncthreads();
    }

    // Epilogue: C/D layout col = lane&15, row = quad*4 + reg
#pragma unroll
    for (int nt = 0; nt < 4; nt++) {
        const int colg = nBase + wc + nt * 16 + l16;
        const int col  = colg - coff;
        const float bv = biasb[col];
#pragma unroll
        for (int mt = 0; mt < MT; mt++) {
#pragma unroll
            for (int rg = 0; rg < 4; rg++) {
                const int row = rowBase + wr + mt * 16 + quad * 4 + rg;
                if (row < M) {
                    float v = (acc[mt][nt][rg] + bv) * scale;
                    if (relu) v = fmaxf(v, 0.f);
                    if (rmode) {
                        int rrow = (rmode == 2) ? (row % KQ) : row;
                        v += bf2f(resid[(size_t)rrow * D_MODEL + col]);
                    }
                    Cb[(size_t)row * ldcb + col] = f2bf(v);
                }
            }
        }
    }
}

// ---------------------------------------------------------------------------
// R11: 256x256 8-phase pipelined GEMM (guide T2+T3+T4+T5 stack).
// 512 thr = 8 waves (2M x 4N), wave tile 128x64, BK=64, LDS 128 KiB
// (2-deep K-tile double buffer for A and B).  Per K-tile: 4 phases of
// {ds_read subtile | stage quarter-tiles -> s_barrier -> lgkmcnt(0) ->
//  setprio(1) 16xMFMA setprio(0) -> s_barrier}, counted vmcnt(8) once per
// K-tile (prefetch stays in flight across barriers -- never vmcnt(0) in the
// main loop).  Staging slot q is rewritten only >=1 barrier after its last
// ds_read (quarters: A-Q0/Q2 last read ph1 -> staged ph2; B last read ph2 ->
// staged ph3; A-Q1/Q3 last read ph3 -> staged ph4).  Same k-XOR permutation
// as gemm_bf16 (measured conflict-free: SQ_LDS_BANK_CONFLICT = 0).
// K-accumulation order identical to gemm_bf16 -> bit-identical results.
// Requires N % 256 == 0, nsplit % 256 == 0, K % 64 == 0; M tail clamped.
// ---------------------------------------------------------------------------
__global__ __launch_bounds__(512, 2) void gemm256(
    const ushort_t* __restrict__ A, const ushort_t* __restrict__ Bt,
    const float* __restrict__ bias, const float* __restrict__ bias2,
    ushort_t* __restrict__ C, ushort_t* __restrict__ C2,
    int M, int N, int K, int nsplit, int relu, float scale,
    const ushort_t* __restrict__ resid, int rmode)
{
    __shared__ ushort_t As[2][256 * 64];
    __shared__ ushort_t Bs[2][256 * 64];

    const int tid  = threadIdx.x;
    const int w    = tid >> 6;
    const int lane = tid & 63;
    const int quad = lane >> 4;
    const int l16  = lane & 15;

    // ---- XCD-aware remap of (by,bx) -> (r,c): row panel r pinned to XCD r&7
    const int nx = gridDim.x, NY = gridDim.y;
    const int bid = blockIdx.y * nx + blockIdx.x;
    const int NYmain = NY & ~7;
    const int Tmain = NYmain * nx;
    int r, c;
    if (bid < Tmain) {
        const int grp = bid / (8 * nx);
        const int rem = bid - grp * 8 * nx;
        r = grp * 8 + (rem & 7);
        c = rem >> 3;
    } else {
        const int rem = bid - Tmain;
        r = NYmain + rem / nx;
        c = rem - (rem / nx) * nx;
    }
    const int rowBase = r * 256;
    const int nBase   = c * 256;
    const int wr = (w >> 2) * 128;   // wave row base (2 groups of 128)
    const int wc = (w & 3) * 64;     // wave col base (4 groups of 64)

    // ---- staging: quarter q = 64 rows = one gld_lds16 per thread (8 KB).
    // thread covers row q*64 + (tid>>3), k-chunk (tid&7)^((tid>>3)&7)
    // (pre-swizzled global source, linear LDS dest -- rule 21).
    const int srow = tid >> 3;
    const int sch  = (tid & 7) ^ (srow & 7);
    const ushort_t* gA[4];
    const ushort_t* gB[4];
#pragma unroll
    for (int q = 0; q < 4; q++) {
        const int lr = q * 64 + srow;
        gA[q] = A  + (size_t)min(rowBase + lr, M - 1) * K + sch * 8;
        gB[q] = Bt + (size_t)(nBase + lr) * K + sch * 8;
    }
    const int sdst = tid * 8;

#define STA(u, q) gld_lds16(gA[q] + (size_t)(u) * 64, &As[(u) & 1][(q) * 4096 + sdst])
#define STB(u, q) gld_lds16(gB[q] + (size_t)(u) * 64, &Bs[(u) & 1][(q) * 4096 + sdst])

#define PH_BEGIN() do { __builtin_amdgcn_s_barrier();                       \
        asm volatile("s_waitcnt lgkmcnt(0)" ::: "memory");                  \
        __builtin_amdgcn_sched_barrier(0);                                  \
        __builtin_amdgcn_s_setprio(1); } while (0)
#define PH_END() do { __builtin_amdgcn_sched_barrier(0);                    \
        __builtin_amdgcn_s_setprio(0);                                      \
        __builtin_amdgcn_s_barrier(); } while (0)

    f32x4 acc[8][4];
#pragma unroll
    for (int i = 0; i < 8; i++)
#pragma unroll
        for (int j = 0; j < 4; j++) acc[i][j] = (f32x4){0.f, 0.f, 0.f, 0.f};

    const int swl = l16 & 7;
    const int NT  = K >> 6;

    // prologue: stage tiles 0 and 1, wait tile 0 (tile 1 stays in flight)
#pragma unroll
    for (int q = 0; q < 4; q++) { STA(0, q); STB(0, q); }
#pragma unroll
    for (int q = 0; q < 4; q++) { STA(1, q); STB(1, q); }
    asm volatile("s_waitcnt vmcnt(8)" ::: "memory");
    __builtin_amdgcn_s_barrier();

    for (int t = 0; t < NT; ++t) {
        const int p = t & 1;
        const ushort_t* Ap = As[p];
        const ushort_t* Bp = Bs[p];
        const bool pf = (t + 2) < NT;

        short8 af[4][2], bf[2][2], bg[2][2];

        // ---- phase 1: (m-half0, n-half0) -- reads A-quarter(low) + B j0,1
#pragma unroll
        for (int i = 0; i < 4; i++)
#pragma unroll
            for (int s = 0; s < 2; s++)
                af[i][s] = *(const short8*)(Ap + (wr + i * 16 + l16) * 64 +
                                            (((4 * s + quad) ^ swl) * 8));
#pragma unroll
        for (int j = 0; j < 2; j++)
#pragma unroll
            for (int s = 0; s < 2; s++)
                bf[j][s] = *(const short8*)(Bp + (wc + j * 16 + l16) * 64 +
                                            (((4 * s + quad) ^ swl) * 8));
        PH_BEGIN();
#pragma unroll
        for (int i = 0; i < 4; i++)
#pragma unroll
            for (int j = 0; j < 2; j++)
#pragma unroll
                for (int s = 0; s < 2; s++)
                    acc[i][j] = __builtin_amdgcn_mfma_f32_16x16x32_bf16(
                        af[i][s], bf[j][s], acc[i][j], 0, 0, 0);
        PH_END();

        // ---- phase 2: (m-half0, n-half1) -- reads B j2,3; stage A-Q0/Q2
#pragma unroll
        for (int j = 0; j < 2; j++)
#pragma unroll
            for (int s = 0; s < 2; s++)
                bg[j][s] = *(const short8*)(Bp + (wc + (j + 2) * 16 + l16) * 64 +
                                            (((4 * s + quad) ^ swl) * 8));
        if (pf) { STA(t + 2, 0); STA(t + 2, 2); }
        PH_BEGIN();
#pragma unroll
        for (int i = 0; i < 4; i++)
#pragma unroll
            for (int j = 0; j < 2; j++)
#pragma unroll
                for (int s = 0; s < 2; s++)
                    acc[i][j + 2] = __builtin_amdgcn_mfma_f32_16x16x32_bf16(
                        af[i][s], bg[j][s], acc[i][j + 2], 0, 0, 0);
        PH_END();

        // ---- phase 3: (m-half1, n-half1) -- reads A-quarter(high); stage B
#pragma unroll
        for (int i = 0; i < 4; i++)
#pragma unroll
            for (int s = 0; s < 2; s++)
                af[i][s] = *(const short8*)(Ap + (wr + 64 + i * 16 + l16) * 64 +
                                            (((4 * s + quad) ^ swl) * 8));
        if (pf) { STB(t + 2, 0); STB(t + 2, 1); STB(t + 2, 2); STB(t + 2, 3); }
        PH_BEGIN();
#pragma unroll
        for (int i = 0; i < 4; i++)
#pragma unroll
            for (int j = 0; j < 2; j++)
#pragma unroll
                for (int s = 0; s < 2; s++)
                    acc[i + 4][j + 2] = __builtin_amdgcn_mfma_f32_16x16x32_bf16(
                        af[i][s], bg[j][s], acc[i + 4][j + 2], 0, 0, 0);
        PH_END();

        // ---- phase 4: (m-half1, n-half0) -- no reads; stage A-Q1/Q3;
        //      counted vmcnt before the tile-closing barrier (never 0 mid-loop)
        if (pf) { STA(t + 2, 1); STA(t + 2, 3); }
        __builtin_amdgcn_s_barrier();
        asm volatile("s_waitcnt lgkmcnt(0)" ::: "memory");
        __builtin_amdgcn_sched_barrier(0);
        __builtin_amdgcn_s_setprio(1);
#pragma unroll
        for (int i = 0; i < 4; i++)
#pragma unroll
            for (int j = 0; j < 2; j++)
#pragma unroll
                for (int s = 0; s < 2; s++)
                    acc[i + 4][j] = __builtin_amdgcn_mfma_f32_16x16x32_bf16(
                        af[i][s], bf[j][s], acc[i + 4][j], 0, 0, 0);
        __builtin_amdgcn_sched_barrier(0);
        __builtin_amdgcn_s_setprio(0);
        if (pf) asm volatile("s_waitcnt vmcnt(8)" ::: "memory");
        else    asm volatile("s_waitcnt vmcnt(0)" ::: "memory");
        __builtin_amdgcn_s_barrier();
    }

#undef STA
#undef STB
#undef PH_BEGIN
#undef PH_END

    // ---- epilogue (same convention as gemm_bf16)
    const float* biasb;
    ushort_t* Cb;
    int coff, ldcb;
    if (nBase < nsplit) { biasb = bias;  Cb = C;  coff = 0;      ldcb = nsplit; }
    else                { biasb = bias2; Cb = C2; coff = nsplit; ldcb = N - nsplit; }

#pragma unroll
    for (int j = 0; j < 4; j++) {
        const int colg = nBase + wc + j * 16 + l16;
        const int col  = colg - coff;
        const float bv = biasb[col];
#pragma unroll
        for (int i = 0; i < 8; i++) {
#pragma unroll
            for (int rg = 0; rg < 4; rg++) {
                const int row = rowBase + wr + i * 16 + quad * 4 + rg;
                if (row < M) {
                    float v = (acc[i][j][rg] + bv) * scale;
                    if (relu) v = fmaxf(v, 0.f);
                    if (rmode) {
                        int rrow = (rmode == 2) ? (row % KQ) : row;
                        v += bf2f(resid[(size_t)rrow * D_MODEL + col]);
                    }
                    Cb[(size_t)row * ldcb + col] = f2bf(v);
                }
            }
        }
    }
}

// ---------------------------------------------------------------------------
// Prep: ONE dispatch = 7 weight transposes (blocks 0..1727) + x convert
// (blocks 1728..2751).
// ---------------------------------------------------------------------------
__global__ __launch_bounds__(256) void prep_all(
    const float* __restrict__ We, const float* __restrict__ wq,
    const float* __restrict__ wk, const float* __restrict__ wv,
    const float* __restrict__ wo, const float* __restrict__ w1,
    const float* __restrict__ w2, const float* __restrict__ x,
    ushort_t* __restrict__ Wet, ushort_t* __restrict__ wqt,
    ushort_t* __restrict__ wkt, ushort_t* __restrict__ wvt,
    ushort_t* __restrict__ wot, ushort_t* __restrict__ w1t,
    ushort_t* __restrict__ w2t, ushort_t* __restrict__ xb)
{
    __shared__ __align__(16) char smem[25600];
    int t = blockIdx.x;
    if (t < 1728) {
        float* tile = (float*)smem;              // [64][65]
        const float* src; ushort_t* dst; int K, N, tx;
        if (t < 384)       {           src = We; dst = Wet; K = 2048; N = 768;  tx = 12; }
        else if (t < 528)  { t -= 384; src = wq; dst = wqt; K = 768;  N = 768;  tx = 12; }
        else if (t < 672)  { t -= 528; src = wk; dst = wkt; K = 768;  N = 768;  tx = 12; }
        else if (t < 816)  { t -= 672; src = wv; dst = wvt; K = 768;  N = 768;  tx = 12; }
        else if (t < 960)  { t -= 816; src = wo; dst = wot; K = 768;  N = 768;  tx = 12; }
        else if (t < 1344) { t -= 960; src = w1; dst = w1t; K = 768;  N = 2048; tx = 32; }
        else               { t -= 1344; src = w2; dst = w2t; K = 2048; N = 768; tx = 12; }
        const int n0 = (t % tx) * 64, k0 = (t / tx) * 64;
        const int tr = threadIdx.x >> 6, tc = threadIdx.x & 63;
#pragma unroll
        for (int i = 0; i < 16; i++) {
            int r = i * 4 + tr;
            tile[r * 65 + tc] = src[(size_t)(k0 + r) * N + n0 + tc];
        }
        __syncthreads();
#pragma unroll
        for (int i = 0; i < 16; i++) {
            int nr = i * 4 + tr;
            dst[(size_t)(n0 + nr) * K + k0 + tc] = f2bf(tile[tc * 65 + nr]);
        }
    } else {
        ushort_t* tile = (ushort_t*)smem;        // [256][50]
        int bx = t - 1728;
        const int b = bx >> 3, f0 = (bx & 7) * 256, tt = threadIdx.x;
        const float* src = x + ((size_t)b * FDIM + f0 + tt) * SEQ;
#pragma unroll
        for (int s = 0; s < SEQ; s++) tile[tt * 50 + s] = f2bf(src[s]);
        __syncthreads();
        for (int s = 0; s < SEQ; s++)
            xb[(size_t)(b * SEQ + s) * FDIM + f0 + tt] = tile[tt * 50 + s];
    }
}

// ---------------------------------------------------------------------------
// LayerNorm, wave-per-row (4 rows/block, shfl-only reduction, no LDS).
// ---------------------------------------------------------------------------
__global__ __launch_bounds__(256) void ln4(
    const void* __restrict__ in, int in_bf16,
    const float* __restrict__ g, const float* __restrict__ be,
    ushort_t* __restrict__ out, float pre_scale, int nrows)
{
    const int w = threadIdx.x >> 6, lane = threadIdx.x & 63;
    const int row = blockIdx.x * 4 + w;
    if (row >= nrows) return;

    float v[12];
    if (in_bf16) {
        const uint_t* p = (const uint_t*)in + (size_t)row * 384;
#pragma unroll
        for (int i = 0; i < 6; i++) {
            uint_t u = p[lane + i * 64];
            v[2 * i]     = bf2f((ushort_t)(u & 0xffff)) * pre_scale;
            v[2 * i + 1] = bf2f((ushort_t)(u >> 16)) * pre_scale;
        }
    } else {
        const float2* p = (const float2*)((const float*)in + (size_t)row * D_MODEL);
#pragma unroll
        for (int i = 0; i < 6; i++) {
            float2 t = p[lane + i * 64];
            v[2 * i] = t.x * pre_scale;
            v[2 * i + 1] = t.y * pre_scale;
        }
    }
    float s = 0.f;
#pragma unroll
    for (int i = 0; i < 12; i++) s += v[i];
#pragma unroll
    for (int off = 32; off > 0; off >>= 1) s += __shfl_xor(s, off);
    const float mean = s * (1.f / D_MODEL);
    float q = 0.f;
#pragma unroll
    for (int i = 0; i < 12; i++) { float d = v[i] - mean; q += d * d; }
#pragma unroll
    for (int off = 32; off > 0; off >>= 1) q += __shfl_xor(q, off);
    const float rstd = rsqrtf(q * (1.f / D_MODEL) + 1e-5f);

    const float2* g2 = (const float2*)g;
    const float2* b2 = (const float2*)be;
    uint_t* op = (uint_t*)out + (size_t)row * 384;
#pragma unroll
    for (int i = 0; i < 6; i++) {
        int j = lane + i * 64;
        float2 gg = g2[j], bb = b2[j];
        ushort_t lo = f2bf((v[2 * i] - mean) * rstd * gg.x + bb.x);
        ushort_t hi = f2bf((v[2 * i + 1] - mean) * rstd * gg.y + bb.y);
        op[j] = (uint_t)lo | ((uint_t)hi << 16);
    }
}

// ---------------------------------------------------------------------------
// MFMA cross-attention, one block per (b,h), 4 waves.  (unchanged — verified)
// ---------------------------------------------------------------------------
__global__ __launch_bounds__(256) void attn_mfma(
    const ushort_t* __restrict__ q, const ushort_t* __restrict__ k,
    const ushort_t* __restrict__ v, ushort_t* __restrict__ ctx)
{
    __shared__ ushort_t Pt[128][72];
    __shared__ ushort_t Vt[96][72];

    const int bh = blockIdx.x;
    const int b = bh >> 3, h = bh & 7;
    const int tid = threadIdx.x;
    const int w = tid >> 6, lane = tid & 63;
    const int quad = lane >> 4, l16 = lane & 15;
    const int mrow0 = 32 * w;

    for (int idx = tid; idx < 96 * 64; idx += 256) {
        int d = idx >> 6, s = idx & 63;
        ushort_t val = 0;
        if (s < SEQ) val = v[(size_t)(b * SEQ + s) * D_MODEL + h * HDIM + d];
        Vt[d][s] = val;
    }

    f32x4 accS[2][4];
#pragma unroll
    for (int i = 0; i < 2; i++)
#pragma unroll
        for (int j = 0; j < 4; j++) accS[i][j] = (f32x4){0.f, 0.f, 0.f, 0.f};

#pragma unroll
    for (int k0 = 0; k0 < HDIM; k0 += 32) {
        short8 af[2], bfr[4];
#pragma unroll
        for (int mt = 0; mt < 2; mt++) {
            int kq = min(mrow0 + mt * 16 + l16, KQ - 1);
            af[mt] = *(const short8*)(q + (size_t)kq * D_MODEL + h * HDIM + k0 + quad * 8);
        }
#pragma unroll
        for (int nt = 0; nt < 4; nt++) {
            int s = min(nt * 16 + l16, SEQ - 1);
            bfr[nt] = *(const short8*)(k + (size_t)(b * SEQ + s) * D_MODEL + h * HDIM + k0 + quad * 8);
        }
#pragma unroll
        for (int mt = 0; mt < 2; mt++)
#pragma unroll
            for (int nt = 0; nt < 4; nt++)
                accS[mt][nt] = __builtin_amdgcn_mfma_f32_16x16x32_bf16(
                    af[mt], bfr[nt], accS[mt][nt], 0, 0, 0);
    }

#pragma unroll
    for (int mt = 0; mt < 2; mt++) {
#pragma unroll
        for (int r = 0; r < 4; r++) {
            float vals[4];
            float vmax = -1e30f;
#pragma unroll
            for (int nt = 0; nt < 4; nt++) {
                vals[nt] = accS[mt][nt][r];
                if (nt * 16 + l16 < SEQ) vmax = fmaxf(vmax, vals[nt]);
            }
#pragma unroll
            for (int off = 1; off < 16; off <<= 1)
                vmax = fmaxf(vmax, __shfl_xor(vmax, off));
            float p[4], psum = 0.f;
#pragma unroll
            for (int nt = 0; nt < 4; nt++) {
                float e = (nt * 16 + l16 < SEQ) ? __expf(vals[nt] - vmax) : 0.f;
                p[nt] = e;
                psum += e;
            }
#pragma unroll
            for (int off = 1; off < 16; off <<= 1)
                psum += __shfl_xor(psum, off);
            const float inv = 1.f / psum;
            const int row = mrow0 + mt * 16 + quad * 4 + r;
#pragma unroll
            for (int nt = 0; nt < 4; nt++)
                Pt[row][nt * 16 + l16] = f2bf(p[nt] * inv);
        }
    }
    __syncthreads();

    f32x4 accO[2][6];
#pragma unroll
    for (int i = 0; i < 2; i++)
#pragma unroll
        for (int j = 0; j < 6; j++) accO[i][j] = (f32x4){0.f, 0.f, 0.f, 0.f};

#pragma unroll
    for (int k0 = 0; k0 < 64; k0 += 32) {
        short8 af[2], bfr[6];
#pragma unroll
        for (int mt = 0; mt < 2; mt++)
            af[mt] = *(const short8*)(&Pt[mrow0 + mt * 16 + l16][k0 + quad * 8]);
#pragma unroll
        for (int nt = 0; nt < 6; nt++)
            bfr[nt] = *(const short8*)(&Vt[nt * 16 + l16][k0 + quad * 8]);
#pragma unroll
        for (int mt = 0; mt < 2; mt++)
#pragma unroll
            for (int nt = 0; nt < 6; nt++)
                accO[mt][nt] = __builtin_amdgcn_mfma_f32_16x16x32_bf16(
                    af[mt], bfr[nt], accO[mt][nt], 0, 0, 0);
    }

#pragma unroll
    for (int mt = 0; mt < 2; mt++) {
#pragma unroll
        for (int r = 0; r < 4; r++) {
            const int kq = mrow0 + mt * 16 + quad * 4 + r;
            if (kq < KQ) {
                size_t oa = (size_t)(b * KQ + kq) * D_MODEL + h * HDIM;
#pragma unroll
                for (int nt = 0; nt < 6; nt++)
                    ctx[oa + nt * 16 + l16] = f2bf(accO[mt][nt][r]);
            }
        }
    }
}

// ---------------------------------------------------------------------------
// GroupFC + fused LN3.  Block = (bgroup of 8 batches, kq).  (verified R7)
// ---------------------------------------------------------------------------
__global__ __launch_bounds__(256) void groupfc3(
    const ushort_t* __restrict__ hb, const float* __restrict__ dp,
    const float* __restrict__ dbias, const float* __restrict__ g3,
    const float* __restrict__ be3, float* __restrict__ out)
{
    __shared__ float dps[D_MODEL * 11];   // [d][g] padded
    __shared__ float hsr[8][D_MODEL];
    __shared__ float gbs[2][D_MODEL];

    const int b0 = blockIdx.x * 8;
    const int kq = blockIdx.y;
    const int tid = threadIdx.x;

    for (int i = tid; i < D_MODEL * GRP; i += 256) {
        int d = i / GRP, g = i - d * GRP;
        dps[d * 11 + g] = dp[(size_t)kq * (D_MODEL * GRP) + i];
    }
    for (int i = tid; i < D_MODEL; i += 256) {
        gbs[0][i] = g3[i];
        gbs[1][i] = be3[i];
    }
#pragma unroll
    for (int bb = 0; bb < 8; bb++) {
#pragma unroll
        for (int i = 0; i < 3; i++) {
            int d = tid + i * 256;
            hsr[bb][d] = bf2f(hb[(size_t)((b0 + bb) * KQ + kq) * D_MODEL + d]);
        }
    }
    __syncthreads();

    const int w = tid >> 6, lane = tid & 63;

#pragma unroll
    for (int rr = 0; rr < 2; rr++) {
        const int r = w * 2 + rr;
        float v[12];
        float s = 0.f;
#pragma unroll
        for (int i = 0; i < 12; i++) { v[i] = hsr[r][lane + i * 64]; s += v[i]; }
#pragma unroll
        for (int off = 32; off > 0; off >>= 1) s += __shfl_xor(s, off);
        const float mean = s * (1.f / D_MODEL);
        float q = 0.f;
#pragma unroll
        for (int i = 0; i < 12; i++) { float d = v[i] - mean; q += d * d; }
#pragma unroll
        for (int off = 32; off > 0; off >>= 1) q += __shfl_xor(q, off);
        const float rstd = rsqrtf(q * (1.f / D_MODEL) + 1e-5f);
#pragma unroll
        for (int i = 0; i < 12; i++) {
            int d = lane + i * 64;
            hsr[r][d] = (v[i] - mean) * rstd * gbs[0][d] + gbs[1][d];
        }
    }
    __syncthreads();

    for (int item = w; item < 8 * GRP; item += 4) {
        int bb = item / GRP, g = item - bb * GRP;
        float a = 0.f;
#pragma unroll
        for (int i = 0; i < 12; i++) {
            int d = lane + i * 64;
            a = fmaf(hsr[bb][d], dps[d * 11 + g], a);
        }
#pragma unroll
        for (int off = 32; off > 0; off >>= 1) a += __shfl_down(a, off);
        if (lane == 0)
            out[(size_t)(b0 + bb) * NCLS + kq * GRP + g] = a + dbias[kq * GRP + g];
    }
}

// ---------------------------------------------------------------------------
extern "C" void kernel_launch(void* const* d_in, const int* in_sizes, int n_in,
                              void* d_out, int out_size, void* d_ws, size_t ws_size,
                              hipStream_t stream)
{
    const float* x   = (const float*)d_in[0];
    const float* We  = (const float*)d_in[1];
    const float* be_ = (const float*)d_in[2];
    const float* qe  = (const float*)d_in[3];
    const float* wq  = (const float*)d_in[4];
    const float* wk  = (const float*)d_in[5];
    const float* wv  = (const float*)d_in[6];
    const float* bq  = (const float*)d_in[7];
    const float* bk  = (const float*)d_in[8];
    const float* bv  = (const float*)d_in[9];
    const float* wo  = (const float*)d_in[10];
    const float* bo  = (const float*)d_in[11];
    const float* w1  = (const float*)d_in[12];
    const float* b1  = (const float*)d_in[13];
    const float* w2  = (const float*)d_in[14];
    const float* b2  = (const float*)d_in[15];
    const float* g1  = (const float*)d_in[16];
    const float* be1 = (const float*)d_in[17];
    const float* g2  = (const float*)d_in[18];
    const float* be2 = (const float*)d_in[19];
    const float* g3  = (const float*)d_in[20];
    const float* be3 = (const float*)d_in[21];
    const float* dp  = (const float*)d_in[22];
    const float* db  = (const float*)d_in[23];
    float* out = (float*)d_out;
    ushort_t* ws = (ushort_t*)d_ws;

    // Workspace (bf16 elems). Region A [0, 27,295,744) time-shared:
    //   phase1: xb | mem | kb | vb     phase2 (>= ffn1): ffh (26,214,400)
    ushort_t* xb  = ws;                      // 6272*2048 = 12,845,056
    ushort_t* mem = xb + 12845056;           // 6272*768  =  4,816,896
    ushort_t* kb  = mem + 4816896;
    ushort_t* vb  = kb + 4816896;
    ushort_t* ffh = ws;                      // 12800*2048 = 26,214,400 (phase2)
    ushort_t* rB  = ws + 27295744;
    ushort_t* Wet = rB;                      // 768*2048 = 1,572,864
    ushort_t* wqt = Wet + 1572864;           // 768*768  =   589,824
    ushort_t* wkt = wqt + 589824;            // wkt/wvt adjacent -> fused kv GEMM
    ushort_t* wvt = wkt + 589824;
    ushort_t* wot = wvt + 589824;
    ushort_t* w1t = wot + 589824;            // 2048*768 = 1,572,864
    ushort_t* w2t = w1t + 1572864;           // 768*2048 = 1,572,864
    ushort_t* tgt = w2t + 1572864;           // 100*768 = 76,800
    ushort_t* qb  = tgt + 76800;
    ushort_t* ctx = qb + 76800;              // 12800*768 = 9,830,400
    ushort_t* t2  = ctx + 9830400;
    ushort_t* hb  = t2 + 9830400;

    dim3 blk(256);
    dim3 blk512(512);
    const float qscale = 1.0f / sqrtf((float)HDIM);

    // 0. prep: 7 weight transposes + x convert, one dispatch
    prep_all<<<dim3(2752), blk, 0, stream>>>(We, wq, wk, wv, wo, w1, w2, x,
                                             Wet, wqt, wkt, wvt, wot, w1t, w2t, xb);

    // 1. mem = relu(xb @ We + b_embed)   [6272 x 768, K=2048]  MT=2 (256^2
    //    tiles would give only 75 blocks -> CU-starved; keep old kernel)
    gemm_bf16<2><<<dim3(6, 98), blk, 0, stream>>>(xb, Wet, be_, be_, mem, mem,
                                                  6272, 768, 2048, 768, 1, 1.f, nullptr, 0);
    // 2. tgt = LN(2*qe)                  [100 rows]
    ln4<<<dim3(25), blk, 0, stream>>>(qe, 0, g1, be1, tgt, 2.0f, KQ);
    // 3. qb = (tgt@wq + bq)/sqrt(96)     [100 x 768, K=768]  MT=1 -> 24 blocks
    gemm_bf16<1><<<dim3(6, 4), blk, 0, stream>>>(tgt, wqt, bq, bq, qb, qb,
                                                 KQ, 768, 768, 768, 0, qscale, nullptr, 0);
    // 4. fused k|v                       [6272 x 1536, K=768]  256^2 -> 150 blocks
    gemm256<<<dim3(6, 25), blk512, 0, stream>>>(mem, wkt, bk, bv, kb, vb,
                                                6272, 1536, 768, 768, 0, 1.f, nullptr, 0);
    // 5. attention -> ctx
    attn_mfma<<<dim3(NB * HEADS), blk, 0, stream>>>(qb, kb, vb, ctx);
    // 6. t2 = ctx@wo + bo + bcast tgt    [12800 x 768, K=768]  256^2 -> 150 blocks
    gemm256<<<dim3(3, 50), blk512, 0, stream>>>(ctx, wot, bo, bo, t2, t2,
                                                12800, 768, 768, 768, 0, 1.f, tgt, 2);
    // 7. t2 = LN(t2)                     [12800 rows]
    ln4<<<dim3(3200), blk, 0, stream>>>(t2, 1, g2, be2, t2, 1.0f, 12800);
    // 8. ffh = relu(t2@w1 + b1)          [12800 x 2048, K=768]  256^2 -> 400 blocks
    gemm256<<<dim3(8, 50), blk512, 0, stream>>>(t2, w1t, b1, b1, ffh, ffh,
                                                12800, 2048, 768, 2048, 1, 1.f, nullptr, 0);
    // 9. hb = ffh@w2 + b2 + t2           [12800 x 768, K=2048]  256^2 -> 150 blocks
    gemm256<<<dim3(3, 50), blk512, 0, stream>>>(ffh, w2t, b2, b2, hb, hb,
                                                12800, 768, 2048, 768, 0, 1.f, t2, 1);
    // 10. GroupFC with fused LN3 -> out (fp32 logits)
    groupfc3<<<dim3(16, KQ), blk, 0, stream>>>(hb, dp, db, g3, be3, out);
}

// Round 2
// 525.191 us; speedup vs baseline: 1.1528x; 1.1528x over previous
//
#include <hip/hip_runtime.h>
#include <math.h>

#define D_MODEL 768
#define HEADS   8
#define HDIM    96
#define SEQ     49
#define KQ      100
#define NB      128
#define FDIM    2048
#define FFD     2048
#define GRP     10
#define NCLS    1000

typedef unsigned short ushort_t;
typedef unsigned int uint_t;
typedef __attribute__((ext_vector_type(8))) short short8;
typedef __attribute__((ext_vector_type(4))) float f32x4;

// ---------------------------------------------------------------------------
// bf16 helpers (RNE rounding)
// ---------------------------------------------------------------------------
__device__ __forceinline__ float bf2f(ushort_t u) {
    uint_t x = ((uint_t)u) << 16;
    return __uint_as_float(x);
}
__device__ __forceinline__ ushort_t f2bf(float f) {
    uint_t x = __float_as_uint(f);
    x += 0x7fffu + ((x >> 16) & 1u);
    return (ushort_t)(x >> 16);
}

// async global->LDS, 16 bytes per lane (lds dest = wave-uniform base + lane*16)
__device__ __forceinline__ void gld_lds16(const void* g, void* l) {
    __builtin_amdgcn_global_load_lds(
        (const __attribute__((address_space(1))) unsigned int*)g,
        (__attribute__((address_space(3))) unsigned int*)l, 16, 0, 0);
}

// ---------------------------------------------------------------------------
// bf16 MFMA GEMM, BK=64, single-buffer (R8 structure — R9's dbuf regressed on
// occupancy), LDS XOR-swizzle (conflict-free, R6), XCD-aware block swizzle
// (R8: FETCH 190->79MB on ffn2).
// R12: big GEMMs back to MT=4 (128x128 tile, wave 64x64, acc 4x4 = m97
// geometry, 2 MFMA per ds_read_b128) with min-waves=3 so the VGPR cap is
// ~170 not 128 — the R10-era MT=4 ran at cap 128 and almost certainly
// spilled.  R11's 256^2 8-phase kernel regressed badly (grids of 150-400
// blocks at 1 block/CU -> 59% CU fill, no TLP to hide phase barriers) and
// is deleted.
// A: [M][K] bf16 row-major.  Bt: [N][K] bf16 row-major.
// Block tile: (MT*32) x 128, 256 thr = 4 waves (2x2), wave = (MT*16)x64.
// K%64==0.  Split-N: cols < nsplit -> C/bias else C2/bias2 (nsplit%128==0).
// Epilogue residual: rmode 0=none, 1=+resid[row][col], 2=+resid[row%KQ][col].
// ---------------------------------------------------------------------------
template <int MT>
__global__ __launch_bounds__(256, (MT == 4 ? 3 : 4)) void gemm_bf16(
    const ushort_t* __restrict__ A, const ushort_t* __restrict__ Bt,
    const float* __restrict__ bias, const float* __restrict__ bias2,
    ushort_t* __restrict__ C, ushort_t* __restrict__ C2,
    int M, int N, int K, int nsplit, int relu, float scale,
    const ushort_t* __restrict__ resid, int rmode)
{
    constexpr int BM  = MT * 32;        // block rows
    constexpr int ACH = MT * 4;         // A chunks (8 rows x 64k each)
    constexpr int NCH = (ACH + 16) / 4; // staging chunks per wave

    __shared__ ushort_t As[BM * 64];
    __shared__ ushort_t Bs[128 * 64];

    const int tid  = threadIdx.x;
    const int w    = tid >> 6;
    const int lane = tid & 63;
    const int quad = lane >> 4;
    const int l16  = lane & 15;

    // ---- XCD-aware remap of (by,bx) -> (r,c) ----
    const int nx = gridDim.x, NY = gridDim.y;
    const int bid = blockIdx.y * nx + blockIdx.x;
    const int NYmain = NY & ~7;
    const int Tmain = NYmain * nx;
    int r, c;
    if (bid < Tmain) {
        const int grp = bid / (8 * nx);
        const int rem = bid - grp * 8 * nx;
        r = grp * 8 + (rem & 7);
        c = rem >> 3;
    } else {
        const int rem = bid - Tmain;
        r = NYmain + rem / nx;
        c = rem - (rem / nx) * nx;
    }
    const int rowBase = r * BM;
    const int nBase   = c * 128;
    const int wr = (w >> 1) * (MT * 16);
    const int wc = (w & 1) * 64;

    const float* biasb;
    ushort_t* Cb;
    int coff, ldcb;
    if (nBase < nsplit) { biasb = bias;  Cb = C;  coff = 0;      ldcb = nsplit; }
    else                { biasb = bias2; Cb = C2; coff = nsplit; ldcb = N - nsplit; }

    f32x4 acc[MT][4];
#pragma unroll
    for (int i = 0; i < MT; i++)
#pragma unroll
        for (int j = 0; j < 4; j++) acc[i][j] = (f32x4){0.f, 0.f, 0.f, 0.f};

    const int lrow = lane >> 3;
    const int ksub = ((lane & 7) ^ ((lane >> 3) & 7)) * 8;

    const ushort_t* gp[NCH];
    ushort_t* lp[NCH];
#pragma unroll
    for (int i = 0; i < NCH; i++) {
        int ch = w + 4 * i;
        if (ch < ACH) {
            int rr = min(rowBase + ch * 8 + lrow, M - 1);
            gp[i] = A + (size_t)rr * K + ksub;
            lp[i] = As + ch * 512 + lane * 8;
        } else {
            int cb = ch - ACH;
            int rr = nBase + cb * 8 + lrow;
            gp[i] = Bt + (size_t)rr * K + ksub;
            lp[i] = Bs + cb * 512 + lane * 8;
        }
    }

    const int swl = l16 & 7;

    for (int k0 = 0; k0 < K; k0 += 64) {
#pragma unroll
        for (int i = 0; i < NCH; i++) gld_lds16(gp[i] + k0, lp[i]);
        __syncthreads();

#pragma unroll
        for (int s = 0; s < 2; s++) {
            const int ks = ((4 * s + quad) ^ swl) * 8;
            short8 af[MT], bfr[4];
#pragma unroll
            for (int mt = 0; mt < MT; mt++)
                af[mt] = *(const short8*)(As + (wr + mt * 16 + l16) * 64 + ks);
#pragma unroll
            for (int nt = 0; nt < 4; nt++)
                bfr[nt] = *(const short8*)(Bs + (wc + nt * 16 + l16) * 64 + ks);
#pragma unroll
            for (int mt = 0; mt < MT; mt++)
#pragma unroll
                for (int nt = 0; nt < 4; nt++)
                    acc[mt][nt] = __builtin_amdgcn_mfma_f32_16x16x32_bf16(
                        af[mt], bfr[nt], acc[mt][nt], 0, 0, 0);
        }
        __syncthreads();
    }

    // Epilogue: C/D layout col = lane&15, row = quad*4 + reg
#pragma unroll
    for (int nt = 0; nt < 4; nt++) {
        const int colg = nBase + wc + nt * 16 + l16;
        const int col  = colg - coff;
        const float bv = biasb[col];
#pragma unroll
        for (int mt = 0; mt < MT; mt++) {
#pragma unroll
            for (int rg = 0; rg < 4; rg++) {
                const int row = rowBase + wr + mt * 16 + quad * 4 + rg;
                if (row < M) {
                    float v = (acc[mt][nt][rg] + bv) * scale;
                    if (relu) v = fmaxf(v, 0.f);
                    if (rmode) {
                        int rrow = (rmode == 2) ? (row % KQ) : row;
                        v += bf2f(resid[(size_t)rrow * D_MODEL + col]);
                    }
                    Cb[(size_t)row * ldcb + col] = f2bf(v);
                }
            }
        }
    }
}

// ---------------------------------------------------------------------------
// Prep: ONE dispatch = 7 weight transposes (blocks 0..1727) + x convert
// (blocks 1728..2751).
// ---------------------------------------------------------------------------
__global__ __launch_bounds__(256) void prep_all(
    const float* __restrict__ We, const float* __restrict__ wq,
    const float* __restrict__ wk, const float* __restrict__ wv,
    const float* __restrict__ wo, const float* __restrict__ w1,
    const float* __restrict__ w2, const float* __restrict__ x,
    ushort_t* __restrict__ Wet, ushort_t* __restrict__ wqt,
    ushort_t* __restrict__ wkt, ushort_t* __restrict__ wvt,
    ushort_t* __restrict__ wot, ushort_t* __restrict__ w1t,
    ushort_t* __restrict__ w2t, ushort_t* __restrict__ xb)
{
    __shared__ __align__(16) char smem[25600];
    int t = blockIdx.x;
    if (t < 1728) {
        float* tile = (float*)smem;              // [64][65]
        const float* src; ushort_t* dst; int K, N, tx;
        if (t < 384)       {           src = We; dst = Wet; K = 2048; N = 768;  tx = 12; }
        else if (t < 528)  { t -= 384; src = wq; dst = wqt; K = 768;  N = 768;  tx = 12; }
        else if (t < 672)  { t -= 528; src = wk; dst = wkt; K = 768;  N = 768;  tx = 12; }
        else if (t < 816)  { t -= 672; src = wv; dst = wvt; K = 768;  N = 768;  tx = 12; }
        else if (t < 960)  { t -= 816; src = wo; dst = wot; K = 768;  N = 768;  tx = 12; }
        else if (t < 1344) { t -= 960; src = w1; dst = w1t; K = 768;  N = 2048; tx = 32; }
        else               { t -= 1344; src = w2; dst = w2t; K = 2048; N = 768; tx = 12; }
        const int n0 = (t % tx) * 64, k0 = (t / tx) * 64;
        const int tr = threadIdx.x >> 6, tc = threadIdx.x & 63;
#pragma unroll
        for (int i = 0; i < 16; i++) {
            int r = i * 4 + tr;
            tile[r * 65 + tc] = src[(size_t)(k0 + r) * N + n0 + tc];
        }
        __syncthreads();
#pragma unroll
        for (int i = 0; i < 16; i++) {
            int nr = i * 4 + tr;
            dst[(size_t)(n0 + nr) * K + k0 + tc] = f2bf(tile[tc * 65 + nr]);
        }
    } else {
        ushort_t* tile = (ushort_t*)smem;        // [256][50]
        int bx = t - 1728;
        const int b = bx >> 3, f0 = (bx & 7) * 256, tt = threadIdx.x;
        const float* src = x + ((size_t)b * FDIM + f0 + tt) * SEQ;
#pragma unroll
        for (int s = 0; s < SEQ; s++) tile[tt * 50 + s] = f2bf(src[s]);
        __syncthreads();
        for (int s = 0; s < SEQ; s++)
            xb[(size_t)(b * SEQ + s) * FDIM + f0 + tt] = tile[tt * 50 + s];
    }
}

// ---------------------------------------------------------------------------
// LayerNorm, wave-per-row (4 rows/block, shfl-only reduction, no LDS).
// ---------------------------------------------------------------------------
__global__ __launch_bounds__(256) void ln4(
    const void* __restrict__ in, int in_bf16,
    const float* __restrict__ g, const float* __restrict__ be,
    ushort_t* __restrict__ out, float pre_scale, int nrows)
{
    const int w = threadIdx.x >> 6, lane = threadIdx.x & 63;
    const int row = blockIdx.x * 4 + w;
    if (row >= nrows) return;

    float v[12];
    if (in_bf16) {
        const uint_t* p = (const uint_t*)in + (size_t)row * 384;
#pragma unroll
        for (int i = 0; i < 6; i++) {
            uint_t u = p[lane + i * 64];
            v[2 * i]     = bf2f((ushort_t)(u & 0xffff)) * pre_scale;
            v[2 * i + 1] = bf2f((ushort_t)(u >> 16)) * pre_scale;
        }
    } else {
        const float2* p = (const float2*)((const float*)in + (size_t)row * D_MODEL);
#pragma unroll
        for (int i = 0; i < 6; i++) {
            float2 t = p[lane + i * 64];
            v[2 * i] = t.x * pre_scale;
            v[2 * i + 1] = t.y * pre_scale;
        }
    }
    float s = 0.f;
#pragma unroll
    for (int i = 0; i < 12; i++) s += v[i];
#pragma unroll
    for (int off = 32; off > 0; off >>= 1) s += __shfl_xor(s, off);
    const float mean = s * (1.f / D_MODEL);
    float q = 0.f;
#pragma unroll
    for (int i = 0; i < 12; i++) { float d = v[i] - mean; q += d * d; }
#pragma unroll
    for (int off = 32; off > 0; off >>= 1) q += __shfl_xor(q, off);
    const float rstd = rsqrtf(q * (1.f / D_MODEL) + 1e-5f);

    const float2* g2 = (const float2*)g;
    const float2* b2 = (const float2*)be;
    uint_t* op = (uint_t*)out + (size_t)row * 384;
#pragma unroll
    for (int i = 0; i < 6; i++) {
        int j = lane + i * 64;
        float2 gg = g2[j], bb = b2[j];
        ushort_t lo = f2bf((v[2 * i] - mean) * rstd * gg.x + bb.x);
        ushort_t hi = f2bf((v[2 * i + 1] - mean) * rstd * gg.y + bb.y);
        op[j] = (uint_t)lo | ((uint_t)hi << 16);
    }
}

// ---------------------------------------------------------------------------
// MFMA cross-attention, one block per (b,h), 4 waves.  (unchanged — verified)
// ---------------------------------------------------------------------------
__global__ __launch_bounds__(256) void attn_mfma(
    const ushort_t* __restrict__ q, const ushort_t* __restrict__ k,
    const ushort_t* __restrict__ v, ushort_t* __restrict__ ctx)
{
    __shared__ ushort_t Pt[128][72];
    __shared__ ushort_t Vt[96][72];

    const int bh = blockIdx.x;
    const int b = bh >> 3, h = bh & 7;
    const int tid = threadIdx.x;
    const int w = tid >> 6, lane = tid & 63;
    const int quad = lane >> 4, l16 = lane & 15;
    const int mrow0 = 32 * w;

    for (int idx = tid; idx < 96 * 64; idx += 256) {
        int d = idx >> 6, s = idx & 63;
        ushort_t val = 0;
        if (s < SEQ) val = v[(size_t)(b * SEQ + s) * D_MODEL + h * HDIM + d];
        Vt[d][s] = val;
    }

    f32x4 accS[2][4];
#pragma unroll
    for (int i = 0; i < 2; i++)
#pragma unroll
        for (int j = 0; j < 4; j++) accS[i][j] = (f32x4){0.f, 0.f, 0.f, 0.f};

#pragma unroll
    for (int k0 = 0; k0 < HDIM; k0 += 32) {
        short8 af[2], bfr[4];
#pragma unroll
        for (int mt = 0; mt < 2; mt++) {
            int kq = min(mrow0 + mt * 16 + l16, KQ - 1);
            af[mt] = *(const short8*)(q + (size_t)kq * D_MODEL + h * HDIM + k0 + quad * 8);
        }
#pragma unroll
        for (int nt = 0; nt < 4; nt++) {
            int s = min(nt * 16 + l16, SEQ - 1);
            bfr[nt] = *(const short8*)(k + (size_t)(b * SEQ + s) * D_MODEL + h * HDIM + k0 + quad * 8);
        }
#pragma unroll
        for (int mt = 0; mt < 2; mt++)
#pragma unroll
            for (int nt = 0; nt < 4; nt++)
                accS[mt][nt] = __builtin_amdgcn_mfma_f32_16x16x32_bf16(
                    af[mt], bfr[nt], accS[mt][nt], 0, 0, 0);
    }

#pragma unroll
    for (int mt = 0; mt < 2; mt++) {
#pragma unroll
        for (int r = 0; r < 4; r++) {
            float vals[4];
            float vmax = -1e30f;
#pragma unroll
            for (int nt = 0; nt < 4; nt++) {
                vals[nt] = accS[mt][nt][r];
                if (nt * 16 + l16 < SEQ) vmax = fmaxf(vmax, vals[nt]);
            }
#pragma unroll
            for (int off = 1; off < 16; off <<= 1)
                vmax = fmaxf(vmax, __shfl_xor(vmax, off));
            float p[4], psum = 0.f;
#pragma unroll
            for (int nt = 0; nt < 4; nt++) {
                float e = (nt * 16 + l16 < SEQ) ? __expf(vals[nt] - vmax) : 0.f;
                p[nt] = e;
                psum += e;
            }
#pragma unroll
            for (int off = 1; off < 16; off <<= 1)
                psum += __shfl_xor(psum, off);
            const float inv = 1.f / psum;
            const int row = mrow0 + mt * 16 + quad * 4 + r;
#pragma unroll
            for (int nt = 0; nt < 4; nt++)
                Pt[row][nt * 16 + l16] = f2bf(p[nt] * inv);
        }
    }
    __syncthreads();

    f32x4 accO[2][6];
#pragma unroll
    for (int i = 0; i < 2; i++)
#pragma unroll
        for (int j = 0; j < 6; j++) accO[i][j] = (f32x4){0.f, 0.f, 0.f, 0.f};

#pragma unroll
    for (int k0 = 0; k0 < 64; k0 += 32) {
        short8 af[2], bfr[6];
#pragma unroll
        for (int mt = 0; mt < 2; mt++)
            af[mt] = *(const short8*)(&Pt[mrow0 + mt * 16 + l16][k0 + quad * 8]);
#pragma unroll
        for (int nt = 0; nt < 6; nt++)
            bfr[nt] = *(const short8*)(&Vt[nt * 16 + l16][k0 + quad * 8]);
#pragma unroll
        for (int mt = 0; mt < 2; mt++)
#pragma unroll
            for (int nt = 0; nt < 6; nt++)
                accO[mt][nt] = __builtin_amdgcn_mfma_f32_16x16x32_bf16(
                    af[mt], bfr[nt], accO[mt][nt], 0, 0, 0);
    }

#pragma unroll
    for (int mt = 0; mt < 2; mt++) {
#pragma unroll
        for (int r = 0; r < 4; r++) {
            const int kq = mrow0 + mt * 16 + quad * 4 + r;
            if (kq < KQ) {
                size_t oa = (size_t)(b * KQ + kq) * D_MODEL + h * HDIM;
#pragma unroll
                for (int nt = 0; nt < 6; nt++)
                    ctx[oa + nt * 16 + l16] = f2bf(accO[mt][nt][r]);
            }
        }
    }
}

// ---------------------------------------------------------------------------
// GroupFC + fused LN3.  Block = (bgroup of 8 batches, kq).  (verified R7)
// ---------------------------------------------------------------------------
__global__ __launch_bounds__(256) void groupfc3(
    const ushort_t* __restrict__ hb, const float* __restrict__ dp,
    const float* __restrict__ dbias, const float* __restrict__ g3,
    const float* __restrict__ be3, float* __restrict__ out)
{
    __shared__ float dps[D_MODEL * 11];   // [d][g] padded
    __shared__ float hsr[8][D_MODEL];
    __shared__ float gbs[2][D_MODEL];

    const int b0 = blockIdx.x * 8;
    const int kq = blockIdx.y;
    const int tid = threadIdx.x;

    for (int i = tid; i < D_MODEL * GRP; i += 256) {
        int d = i / GRP, g = i - d * GRP;
        dps[d * 11 + g] = dp[(size_t)kq * (D_MODEL * GRP) + i];
    }
    for (int i = tid; i < D_MODEL; i += 256) {
        gbs[0][i] = g3[i];
        gbs[1][i] = be3[i];
    }
#pragma unroll
    for (int bb = 0; bb < 8; bb++) {
#pragma unroll
        for (int i = 0; i < 3; i++) {
            int d = tid + i * 256;
            hsr[bb][d] = bf2f(hb[(size_t)((b0 + bb) * KQ + kq) * D_MODEL + d]);
        }
    }
    __syncthreads();

    const int w = tid >> 6, lane = tid & 63;

#pragma unroll
    for (int rr = 0; rr < 2; rr++) {
        const int r = w * 2 + rr;
        float v[12];
        float s = 0.f;
#pragma unroll
        for (int i = 0; i < 12; i++) { v[i] = hsr[r][lane + i * 64]; s += v[i]; }
#pragma unroll
        for (int off = 32; off > 0; off >>= 1) s += __shfl_xor(s, off);
        const float mean = s * (1.f / D_MODEL);
        float q = 0.f;
#pragma unroll
        for (int i = 0; i < 12; i++) { float d = v[i] - mean; q += d * d; }
#pragma unroll
        for (int off = 32; off > 0; off >>= 1) q += __shfl_xor(q, off);
        const float rstd = rsqrtf(q * (1.f / D_MODEL) + 1e-5f);
#pragma unroll
        for (int i = 0; i < 12; i++) {
            int d = lane + i * 64;
            hsr[r][d] = (v[i] - mean) * rstd * gbs[0][d] + gbs[1][d];
        }
    }
    __syncthreads();

    for (int item = w; item < 8 * GRP; item += 4) {
        int bb = item / GRP, g = item - bb * GRP;
        float a = 0.f;
#pragma unroll
        for (int i = 0; i < 12; i++) {
            int d = lane + i * 64;
            a = fmaf(hsr[bb][d], dps[d * 11 + g], a);
        }
#pragma unroll
        for (int off = 32; off > 0; off >>= 1) a += __shfl_down(a, off);
        if (lane == 0)
            out[(size_t)(b0 + bb) * NCLS + kq * GRP + g] = a + dbias[kq * GRP + g];
    }
}

// ---------------------------------------------------------------------------
extern "C" void kernel_launch(void* const* d_in, const int* in_sizes, int n_in,
                              void* d_out, int out_size, void* d_ws, size_t ws_size,
                              hipStream_t stream)
{
    const float* x   = (const float*)d_in[0];
    const float* We  = (const float*)d_in[1];
    const float* be_ = (const float*)d_in[2];
    const float* qe  = (const float*)d_in[3];
    const float* wq  = (const float*)d_in[4];
    const float* wk  = (const float*)d_in[5];
    const float* wv  = (const float*)d_in[6];
    const float* bq  = (const float*)d_in[7];
    const float* bk  = (const float*)d_in[8];
    const float* bv  = (const float*)d_in[9];
    const float* wo  = (const float*)d_in[10];
    const float* bo  = (const float*)d_in[11];
    const float* w1  = (const float*)d_in[12];
    const float* b1  = (const float*)d_in[13];
    const float* w2  = (const float*)d_in[14];
    const float* b2  = (const float*)d_in[15];
    const float* g1  = (const float*)d_in[16];
    const float* be1 = (const float*)d_in[17];
    const float* g2  = (const float*)d_in[18];
    const float* be2 = (const float*)d_in[19];
    const float* g3  = (const float*)d_in[20];
    const float* be3 = (const float*)d_in[21];
    const float* dp  = (const float*)d_in[22];
    const float* db  = (const float*)d_in[23];
    float* out = (float*)d_out;
    ushort_t* ws = (ushort_t*)d_ws;

    // Workspace (bf16 elems). Region A [0, 27,295,744) time-shared:
    //   phase1: xb | mem | kb | vb     phase2 (>= ffn1): ffh (26,214,400)
    ushort_t* xb  = ws;                      // 6272*2048 = 12,845,056
    ushort_t* mem = xb + 12845056;           // 6272*768  =  4,816,896
    ushort_t* kb  = mem + 4816896;
    ushort_t* vb  = kb + 4816896;
    ushort_t* ffh = ws;                      // 12800*2048 = 26,214,400 (phase2)
    ushort_t* rB  = ws + 27295744;
    ushort_t* Wet = rB;                      // 768*2048 = 1,572,864
    ushort_t* wqt = Wet + 1572864;           // 768*768  =   589,824
    ushort_t* wkt = wqt + 589824;            // wkt/wvt adjacent -> fused kv GEMM
    ushort_t* wvt = wkt + 589824;
    ushort_t* wot = wvt + 589824;
    ushort_t* w1t = wot + 589824;            // 2048*768 = 1,572,864
    ushort_t* w2t = w1t + 1572864;           // 768*2048 = 1,572,864
    ushort_t* tgt = w2t + 1572864;           // 100*768 = 76,800
    ushort_t* qb  = tgt + 76800;
    ushort_t* ctx = qb + 76800;              // 12800*768 = 9,830,400
    ushort_t* t2  = ctx + 9830400;
    ushort_t* hb  = t2 + 9830400;

    dim3 blk(256);
    const float qscale = 1.0f / sqrtf((float)HDIM);

    // 0. prep: 7 weight transposes + x convert, one dispatch
    prep_all<<<dim3(2752), blk, 0, stream>>>(We, wq, wk, wv, wo, w1, w2, x,
                                             Wet, wqt, wkt, wvt, wot, w1t, w2t, xb);

    // 1. mem = relu(xb @ We + b_embed)   [6272 x 768, K=2048]  MT=4 -> 294 blocks
    gemm_bf16<4><<<dim3(6, 49), blk, 0, stream>>>(xb, Wet, be_, be_, mem, mem,
                                                  6272, 768, 2048, 768, 1, 1.f, nullptr, 0);
    // 2. tgt = LN(2*qe)                  [100 rows]
    ln4<<<dim3(25), blk, 0, stream>>>(qe, 0, g1, be1, tgt, 2.0f, KQ);
    // 3. qb = (tgt@wq + bq)/sqrt(96)     [100 x 768, K=768]  MT=1 -> 24 blocks
    gemm_bf16<1><<<dim3(6, 4), blk, 0, stream>>>(tgt, wqt, bq, bq, qb, qb,
                                                 KQ, 768, 768, 768, 0, qscale, nullptr, 0);
    // 4. fused k|v                       [6272 x 1536, K=768]  MT=4 -> 588 blocks
    gemm_bf16<4><<<dim3(12, 49), blk, 0, stream>>>(mem, wkt, bk, bv, kb, vb,
                                                   6272, 1536, 768, 768, 0, 1.f, nullptr, 0);
    // 5. attention -> ctx
    attn_mfma<<<dim3(NB * HEADS), blk, 0, stream>>>(qb, kb, vb, ctx);
    // 6. t2 = ctx@wo + bo + bcast tgt    [12800 x 768, K=768]  MT=4 -> 600 blocks
    gemm_bf16<4><<<dim3(6, 100), blk, 0, stream>>>(ctx, wot, bo, bo, t2, t2,
                                                   12800, 768, 768, 768, 0, 1.f, tgt, 2);
    // 7. t2 = LN(t2)                     [12800 rows]
    ln4<<<dim3(3200), blk, 0, stream>>>(t2, 1, g2, be2, t2, 1.0f, 12800);
    // 8. ffh = relu(t2@w1 + b1)          [12800 x 2048, K=768]  MT=4 -> 1600 blocks
    gemm_bf16<4><<<dim3(16, 100), blk, 0, stream>>>(t2, w1t, b1, b1, ffh, ffh,
                                                    12800, 2048, 768, 2048, 1, 1.f, nullptr, 0);
    // 9. hb = ffh@w2 + b2 + t2           [12800 x 768, K=2048]  MT=4 -> 600 blocks
    gemm_bf16<4><<<dim3(6, 100), blk, 0, stream>>>(ffh, w2t, b2, b2, hb, hb,
                                                   12800, 768, 2048, 768, 0, 1.f, t2, 1);
    // 10. GroupFC with fused LN3 -> out (fp32 logits)
    groupfc3<<<dim3(16, KQ), blk, 0, stream>>>(hb, dp, db, g3, be3, out);
}

// Round 3
// 451.391 us; speedup vs baseline: 1.3413x; 1.1635x over previous
//
#include <hip/hip_runtime.h>
#include <math.h>

#define D_MODEL 768
#define HEADS   8
#define HDIM    96
#define SEQ     49
#define KQ      100
#define NB      128
#define FDIM    2048
#define FFD     2048
#define GRP     10
#define NCLS    1000

typedef unsigned short ushort_t;
typedef unsigned int uint_t;
typedef __attribute__((ext_vector_type(8))) short short8;
typedef __attribute__((ext_vector_type(4))) float f32x4;

// ---------------------------------------------------------------------------
// bf16 helpers (RNE rounding)
// ---------------------------------------------------------------------------
__device__ __forceinline__ float bf2f(ushort_t u) {
    uint_t x = ((uint_t)u) << 16;
    return __uint_as_float(x);
}
__device__ __forceinline__ ushort_t f2bf(float f) {
    uint_t x = __float_as_uint(f);
    x += 0x7fffu + ((x >> 16) & 1u);
    return (ushort_t)(x >> 16);
}

// async global->LDS, 16 bytes per lane (lds dest = wave-uniform base + lane*16)
__device__ __forceinline__ void gld_lds16(const void* g, void* l) {
    __builtin_amdgcn_global_load_lds(
        (const __attribute__((address_space(1))) unsigned int*)g,
        (__attribute__((address_space(3))) unsigned int*)l, 16, 0, 0);
}

// ---------------------------------------------------------------------------
// bf16 MFMA GEMM, BK=64, single-buffer, LDS XOR-swizzle (conflict-free, R6),
// XCD-aware block swizzle (R8).  R12/R11 post-mortem: MT=4 (525us) and the
// 256^2 8-phase kernel (605us) BOTH lose to this MT=2 structure (504us) —
// at K=768..2048 (12-32 K-steps) TLP at ~3.6 blocks/CU hides the per-K-step
// barrier drain better than higher per-wave intensity at 2 blocks/CU.
// R13: LDS-staged coalesced epilogue.  Old epilogue = 32 scalar 2B stores
// per thread (32B transactions, lines leave L2 partially dirty): measured
// WRITE_SIZE = 1.84x ideal on ffn1 (96.6 vs 52.4 MB).  Now the C tile is
// staged in the (dead) LDS staging buffer and written 16B/lane, full-line.
// Values bit-identical (same rounding, same order) -> absmax unchanged.
// A: [M][K] bf16 row-major.  Bt: [N][K] bf16 row-major.
// Block tile: (MT*32) x 128, 256 thr = 4 waves (2x2), wave = (MT*16)x64.
// K%64==0.  Split-N: cols < nsplit -> C/bias else C2/bias2 (nsplit%128==0).
// Epilogue residual: rmode 0=none, 1=+resid[row][col], 2=+resid[row%KQ][col].
// ---------------------------------------------------------------------------
template <int MT>
__global__ __launch_bounds__(256, 4) void gemm_bf16(
    const ushort_t* __restrict__ A, const ushort_t* __restrict__ Bt,
    const float* __restrict__ bias, const float* __restrict__ bias2,
    ushort_t* __restrict__ C, ushort_t* __restrict__ C2,
    int M, int N, int K, int nsplit, int relu, float scale,
    const ushort_t* __restrict__ resid, int rmode)
{
    constexpr int BM  = MT * 32;        // block rows
    constexpr int ACH = MT * 4;         // A chunks (8 rows x 64k each)
    constexpr int NCH = (ACH + 16) / 4; // staging chunks per wave

    // staging (As|Bs) and the epilogue C tile share one allocation:
    // staging = BM*64 + 128*64 elems;  C tile = BM*128 elems (<= staging).
    __shared__ ushort_t smem[BM * 64 + 128 * 64];
    ushort_t* As = smem;
    ushort_t* Bs = smem + BM * 64;

    const int tid  = threadIdx.x;
    const int w    = tid >> 6;
    const int lane = tid & 63;
    const int quad = lane >> 4;
    const int l16  = lane & 15;

    // ---- XCD-aware remap of (by,bx) -> (r,c) ----
    const int nx = gridDim.x, NY = gridDim.y;
    const int bid = blockIdx.y * nx + blockIdx.x;
    const int NYmain = NY & ~7;
    const int Tmain = NYmain * nx;
    int r, c;
    if (bid < Tmain) {
        const int grp = bid / (8 * nx);
        const int rem = bid - grp * 8 * nx;
        r = grp * 8 + (rem & 7);
        c = rem >> 3;
    } else {
        const int rem = bid - Tmain;
        r = NYmain + rem / nx;
        c = rem - (rem / nx) * nx;
    }
    const int rowBase = r * BM;
    const int nBase   = c * 128;
    const int wr = (w >> 1) * (MT * 16);
    const int wc = (w & 1) * 64;

    const float* biasb;
    ushort_t* Cb;
    int coff, ldcb;
    if (nBase < nsplit) { biasb = bias;  Cb = C;  coff = 0;      ldcb = nsplit; }
    else                { biasb = bias2; Cb = C2; coff = nsplit; ldcb = N - nsplit; }

    f32x4 acc[MT][4];
#pragma unroll
    for (int i = 0; i < MT; i++)
#pragma unroll
        for (int j = 0; j < 4; j++) acc[i][j] = (f32x4){0.f, 0.f, 0.f, 0.f};

    const int lrow = lane >> 3;
    const int ksub = ((lane & 7) ^ ((lane >> 3) & 7)) * 8;

    const ushort_t* gp[NCH];
    ushort_t* lp[NCH];
#pragma unroll
    for (int i = 0; i < NCH; i++) {
        int ch = w + 4 * i;
        if (ch < ACH) {
            int rr = min(rowBase + ch * 8 + lrow, M - 1);
            gp[i] = A + (size_t)rr * K + ksub;
            lp[i] = As + ch * 512 + lane * 8;
        } else {
            int cb = ch - ACH;
            int rr = nBase + cb * 8 + lrow;
            gp[i] = Bt + (size_t)rr * K + ksub;
            lp[i] = Bs + cb * 512 + lane * 8;
        }
    }

    const int swl = l16 & 7;

    for (int k0 = 0; k0 < K; k0 += 64) {
#pragma unroll
        for (int i = 0; i < NCH; i++) gld_lds16(gp[i] + k0, lp[i]);
        __syncthreads();

#pragma unroll
        for (int s = 0; s < 2; s++) {
            const int ks = ((4 * s + quad) ^ swl) * 8;
            short8 af[MT], bfr[4];
#pragma unroll
            for (int mt = 0; mt < MT; mt++)
                af[mt] = *(const short8*)(As + (wr + mt * 16 + l16) * 64 + ks);
#pragma unroll
            for (int nt = 0; nt < 4; nt++)
                bfr[nt] = *(const short8*)(Bs + (wc + nt * 16 + l16) * 64 + ks);
#pragma unroll
            for (int mt = 0; mt < MT; mt++)
#pragma unroll
                for (int nt = 0; nt < 4; nt++)
                    acc[mt][nt] = __builtin_amdgcn_mfma_f32_16x16x32_bf16(
                        af[mt], bfr[nt], acc[mt][nt], 0, 0, 0);
        }
        __syncthreads();
    }

    // ---- Epilogue (R13): bias/relu/resid as before (C/D layout: col=l16,
    // row=quad*4+rg), but store via LDS so HBM writes are full 16B/lane
    // coalesced lines instead of 32B quad fragments.
    ushort_t* Ct = smem;   // BM*128, staging is dead after final barrier
#pragma unroll
    for (int nt = 0; nt < 4; nt++) {
        const int colg = nBase + wc + nt * 16 + l16;
        const int col  = colg - coff;
        const float bv = biasb[col];
#pragma unroll
        for (int mt = 0; mt < MT; mt++) {
#pragma unroll
            for (int rg = 0; rg < 4; rg++) {
                const int lr  = wr + mt * 16 + quad * 4 + rg;   // local row
                const int row = rowBase + lr;
                float v = (acc[mt][nt][rg] + bv) * scale;
                if (relu) v = fmaxf(v, 0.f);
                if (rmode && row < M) {
                    int rrow = (rmode == 2) ? (row % KQ) : row;
                    v += bf2f(resid[(size_t)rrow * D_MODEL + col]);
                }
                Ct[lr * 128 + wc + nt * 16 + l16] = f2bf(v);
            }
        }
    }
    __syncthreads();

    const int ocol = (tid & 15) * 8;          // 16B chunk within the 128 cols
    const int ceff = nBase - coff + ocol;
#pragma unroll
    for (int i = 0; i < BM / 16; i++) {
        const int lr  = i * 16 + (tid >> 4);
        const int row = rowBase + lr;
        if (row < M) {
            short8 vv = *(const short8*)(Ct + lr * 128 + ocol);
            *(short8*)(Cb + (size_t)row * ldcb + ceff) = vv;
        }
    }
}

// ---------------------------------------------------------------------------
// Prep: ONE dispatch = 7 weight transposes (blocks 0..1727) + x convert
// (blocks 1728..2751).
// ---------------------------------------------------------------------------
__global__ __launch_bounds__(256) void prep_all(
    const float* __restrict__ We, const float* __restrict__ wq,
    const float* __restrict__ wk, const float* __restrict__ wv,
    const float* __restrict__ wo, const float* __restrict__ w1,
    const float* __restrict__ w2, const float* __restrict__ x,
    ushort_t* __restrict__ Wet, ushort_t* __restrict__ wqt,
    ushort_t* __restrict__ wkt, ushort_t* __restrict__ wvt,
    ushort_t* __restrict__ wot, ushort_t* __restrict__ w1t,
    ushort_t* __restrict__ w2t, ushort_t* __restrict__ xb)
{
    __shared__ __align__(16) char smem[25600];
    int t = blockIdx.x;
    if (t < 1728) {
        float* tile = (float*)smem;              // [64][65]
        const float* src; ushort_t* dst; int K, N, tx;
        if (t < 384)       {           src = We; dst = Wet; K = 2048; N = 768;  tx = 12; }
        else if (t < 528)  { t -= 384; src = wq; dst = wqt; K = 768;  N = 768;  tx = 12; }
        else if (t < 672)  { t -= 528; src = wk; dst = wkt; K = 768;  N = 768;  tx = 12; }
        else if (t < 816)  { t -= 672; src = wv; dst = wvt; K = 768;  N = 768;  tx = 12; }
        else if (t < 960)  { t -= 816; src = wo; dst = wot; K = 768;  N = 768;  tx = 12; }
        else if (t < 1344) { t -= 960; src = w1; dst = w1t; K = 768;  N = 2048; tx = 32; }
        else               { t -= 1344; src = w2; dst = w2t; K = 2048; N = 768; tx = 12; }
        const int n0 = (t % tx) * 64, k0 = (t / tx) * 64;
        const int tr = threadIdx.x >> 6, tc = threadIdx.x & 63;
#pragma unroll
        for (int i = 0; i < 16; i++) {
            int r = i * 4 + tr;
            tile[r * 65 + tc] = src[(size_t)(k0 + r) * N + n0 + tc];
        }
        __syncthreads();
#pragma unroll
        for (int i = 0; i < 16; i++) {
            int nr = i * 4 + tr;
            dst[(size_t)(n0 + nr) * K + k0 + tc] = f2bf(tile[tc * 65 + nr]);
        }
    } else {
        ushort_t* tile = (ushort_t*)smem;        // [256][50]
        int bx = t - 1728;
        const int b = bx >> 3, f0 = (bx & 7) * 256, tt = threadIdx.x;
        const float* src = x + ((size_t)b * FDIM + f0 + tt) * SEQ;
#pragma unroll
        for (int s = 0; s < SEQ; s++) tile[tt * 50 + s] = f2bf(src[s]);
        __syncthreads();
        for (int s = 0; s < SEQ; s++)
            xb[(size_t)(b * SEQ + s) * FDIM + f0 + tt] = tile[tt * 50 + s];
    }
}

// ---------------------------------------------------------------------------
// LayerNorm, wave-per-row (4 rows/block, shfl-only reduction, no LDS).
// ---------------------------------------------------------------------------
__global__ __launch_bounds__(256) void ln4(
    const void* __restrict__ in, int in_bf16,
    const float* __restrict__ g, const float* __restrict__ be,
    ushort_t* __restrict__ out, float pre_scale, int nrows)
{
    const int w = threadIdx.x >> 6, lane = threadIdx.x & 63;
    const int row = blockIdx.x * 4 + w;
    if (row >= nrows) return;

    float v[12];
    if (in_bf16) {
        const uint_t* p = (const uint_t*)in + (size_t)row * 384;
#pragma unroll
        for (int i = 0; i < 6; i++) {
            uint_t u = p[lane + i * 64];
            v[2 * i]     = bf2f((ushort_t)(u & 0xffff)) * pre_scale;
            v[2 * i + 1] = bf2f((ushort_t)(u >> 16)) * pre_scale;
        }
    } else {
        const float2* p = (const float2*)((const float*)in + (size_t)row * D_MODEL);
#pragma unroll
        for (int i = 0; i < 6; i++) {
            float2 t = p[lane + i * 64];
            v[2 * i] = t.x * pre_scale;
            v[2 * i + 1] = t.y * pre_scale;
        }
    }
    float s = 0.f;
#pragma unroll
    for (int i = 0; i < 12; i++) s += v[i];
#pragma unroll
    for (int off = 32; off > 0; off >>= 1) s += __shfl_xor(s, off);
    const float mean = s * (1.f / D_MODEL);
    float q = 0.f;
#pragma unroll
    for (int i = 0; i < 12; i++) { float d = v[i] - mean; q += d * d; }
#pragma unroll
    for (int off = 32; off > 0; off >>= 1) q += __shfl_xor(q, off);
    const float rstd = rsqrtf(q * (1.f / D_MODEL) + 1e-5f);

    const float2* g2 = (const float2*)g;
    const float2* b2 = (const float2*)be;
    uint_t* op = (uint_t*)out + (size_t)row * 384;
#pragma unroll
    for (int i = 0; i < 6; i++) {
        int j = lane + i * 64;
        float2 gg = g2[j], bb = b2[j];
        ushort_t lo = f2bf((v[2 * i] - mean) * rstd * gg.x + bb.x);
        ushort_t hi = f2bf((v[2 * i + 1] - mean) * rstd * gg.y + bb.y);
        op[j] = (uint_t)lo | ((uint_t)hi << 16);
    }
}

// ---------------------------------------------------------------------------
// MFMA cross-attention, one block per (b,h), 4 waves.  (unchanged — verified)
// ---------------------------------------------------------------------------
__global__ __launch_bounds__(256) void attn_mfma(
    const ushort_t* __restrict__ q, const ushort_t* __restrict__ k,
    const ushort_t* __restrict__ v, ushort_t* __restrict__ ctx)
{
    __shared__ ushort_t Pt[128][72];
    __shared__ ushort_t Vt[96][72];

    const int bh = blockIdx.x;
    const int b = bh >> 3, h = bh & 7;
    const int tid = threadIdx.x;
    const int w = tid >> 6, lane = tid & 63;
    const int quad = lane >> 4, l16 = lane & 15;
    const int mrow0 = 32 * w;

    for (int idx = tid; idx < 96 * 64; idx += 256) {
        int d = idx >> 6, s = idx & 63;
        ushort_t val = 0;
        if (s < SEQ) val = v[(size_t)(b * SEQ + s) * D_MODEL + h * HDIM + d];
        Vt[d][s] = val;
    }

    f32x4 accS[2][4];
#pragma unroll
    for (int i = 0; i < 2; i++)
#pragma unroll
        for (int j = 0; j < 4; j++) accS[i][j] = (f32x4){0.f, 0.f, 0.f, 0.f};

#pragma unroll
    for (int k0 = 0; k0 < HDIM; k0 += 32) {
        short8 af[2], bfr[4];
#pragma unroll
        for (int mt = 0; mt < 2; mt++) {
            int kq = min(mrow0 + mt * 16 + l16, KQ - 1);
            af[mt] = *(const short8*)(q + (size_t)kq * D_MODEL + h * HDIM + k0 + quad * 8);
        }
#pragma unroll
        for (int nt = 0; nt < 4; nt++) {
            int s = min(nt * 16 + l16, SEQ - 1);
            bfr[nt] = *(const short8*)(k + (size_t)(b * SEQ + s) * D_MODEL + h * HDIM + k0 + quad * 8);
        }
#pragma unroll
        for (int mt = 0; mt < 2; mt++)
#pragma unroll
            for (int nt = 0; nt < 4; nt++)
                accS[mt][nt] = __builtin_amdgcn_mfma_f32_16x16x32_bf16(
                    af[mt], bfr[nt], accS[mt][nt], 0, 0, 0);
    }

#pragma unroll
    for (int mt = 0; mt < 2; mt++) {
#pragma unroll
        for (int r = 0; r < 4; r++) {
            float vals[4];
            float vmax = -1e30f;
#pragma unroll
            for (int nt = 0; nt < 4; nt++) {
                vals[nt] = accS[mt][nt][r];
                if (nt * 16 + l16 < SEQ) vmax = fmaxf(vmax, vals[nt]);
            }
#pragma unroll
            for (int off = 1; off < 16; off <<= 1)
                vmax = fmaxf(vmax, __shfl_xor(vmax, off));
            float p[4], psum = 0.f;
#pragma unroll
            for (int nt = 0; nt < 4; nt++) {
                float e = (nt * 16 + l16 < SEQ) ? __expf(vals[nt] - vmax) : 0.f;
                p[nt] = e;
                psum += e;
            }
#pragma unroll
            for (int off = 1; off < 16; off <<= 1)
                psum += __shfl_xor(psum, off);
            const float inv = 1.f / psum;
            const int row = mrow0 + mt * 16 + quad * 4 + r;
#pragma unroll
            for (int nt = 0; nt < 4; nt++)
                Pt[row][nt * 16 + l16] = f2bf(p[nt] * inv);
        }
    }
    __syncthreads();

    f32x4 accO[2][6];
#pragma unroll
    for (int i = 0; i < 2; i++)
#pragma unroll
        for (int j = 0; j < 6; j++) accO[i][j] = (f32x4){0.f, 0.f, 0.f, 0.f};

#pragma unroll
    for (int k0 = 0; k0 < 64; k0 += 32) {
        short8 af[2], bfr[6];
#pragma unroll
        for (int mt = 0; mt < 2; mt++)
            af[mt] = *(const short8*)(&Pt[mrow0 + mt * 16 + l16][k0 + quad * 8]);
#pragma unroll
        for (int nt = 0; nt < 6; nt++)
            bfr[nt] = *(const short8*)(&Vt[nt * 16 + l16][k0 + quad * 8]);
#pragma unroll
        for (int mt = 0; mt < 2; mt++)
#pragma unroll
            for (int nt = 0; nt < 6; nt++)
                accO[mt][nt] = __builtin_amdgcn_mfma_f32_16x16x32_bf16(
                    af[mt], bfr[nt], accO[mt][nt], 0, 0, 0);
    }

#pragma unroll
    for (int mt = 0; mt < 2; mt++) {
#pragma unroll
        for (int r = 0; r < 4; r++) {
            const int kq = mrow0 + mt * 16 + quad * 4 + r;
            if (kq < KQ) {
                size_t oa = (size_t)(b * KQ + kq) * D_MODEL + h * HDIM;
#pragma unroll
                for (int nt = 0; nt < 6; nt++)
                    ctx[oa + nt * 16 + l16] = f2bf(accO[mt][nt][r]);
            }
        }
    }
}

// ---------------------------------------------------------------------------
// GroupFC + fused LN3.  Block = (bgroup of 8 batches, kq).  (verified R7)
// ---------------------------------------------------------------------------
__global__ __launch_bounds__(256) void groupfc3(
    const ushort_t* __restrict__ hb, const float* __restrict__ dp,
    const float* __restrict__ dbias, const float* __restrict__ g3,
    const float* __restrict__ be3, float* __restrict__ out)
{
    __shared__ float dps[D_MODEL * 11];   // [d][g] padded
    __shared__ float hsr[8][D_MODEL];
    __shared__ float gbs[2][D_MODEL];

    const int b0 = blockIdx.x * 8;
    const int kq = blockIdx.y;
    const int tid = threadIdx.x;

    for (int i = tid; i < D_MODEL * GRP; i += 256) {
        int d = i / GRP, g = i - d * GRP;
        dps[d * 11 + g] = dp[(size_t)kq * (D_MODEL * GRP) + i];
    }
    for (int i = tid; i < D_MODEL; i += 256) {
        gbs[0][i] = g3[i];
        gbs[1][i] = be3[i];
    }
#pragma unroll
    for (int bb = 0; bb < 8; bb++) {
#pragma unroll
        for (int i = 0; i < 3; i++) {
            int d = tid + i * 256;
            hsr[bb][d] = bf2f(hb[(size_t)((b0 + bb) * KQ + kq) * D_MODEL + d]);
        }
    }
    __syncthreads();

    const int w = tid >> 6, lane = tid & 63;

#pragma unroll
    for (int rr = 0; rr < 2; rr++) {
        const int r = w * 2 + rr;
        float v[12];
        float s = 0.f;
#pragma unroll
        for (int i = 0; i < 12; i++) { v[i] = hsr[r][lane + i * 64]; s += v[i]; }
#pragma unroll
        for (int off = 32; off > 0; off >>= 1) s += __shfl_xor(s, off);
        const float mean = s * (1.f / D_MODEL);
        float q = 0.f;
#pragma unroll
        for (int i = 0; i < 12; i++) { float d = v[i] - mean; q += d * d; }
#pragma unroll
        for (int off = 32; off > 0; off >>= 1) q += __shfl_xor(q, off);
        const float rstd = rsqrtf(q * (1.f / D_MODEL) + 1e-5f);
#pragma unroll
        for (int i = 0; i < 12; i++) {
            int d = lane + i * 64;
            hsr[r][d] = (v[i] - mean) * rstd * gbs[0][d] + gbs[1][d];
        }
    }
    __syncthreads();

    for (int item = w; item < 8 * GRP; item += 4) {
        int bb = item / GRP, g = item - bb * GRP;
        float a = 0.f;
#pragma unroll
        for (int i = 0; i < 12; i++) {
            int d = lane + i * 64;
            a = fmaf(hsr[bb][d], dps[d * 11 + g], a);
        }
#pragma unroll
        for (int off = 32; off > 0; off >>= 1) a += __shfl_down(a, off);
        if (lane == 0)
            out[(size_t)(b0 + bb) * NCLS + kq * GRP + g] = a + dbias[kq * GRP + g];
    }
}

// ---------------------------------------------------------------------------
extern "C" void kernel_launch(void* const* d_in, const int* in_sizes, int n_in,
                              void* d_out, int out_size, void* d_ws, size_t ws_size,
                              hipStream_t stream)
{
    const float* x   = (const float*)d_in[0];
    const float* We  = (const float*)d_in[1];
    const float* be_ = (const float*)d_in[2];
    const float* qe  = (const float*)d_in[3];
    const float* wq  = (const float*)d_in[4];
    const float* wk  = (const float*)d_in[5];
    const float* wv  = (const float*)d_in[6];
    const float* bq  = (const float*)d_in[7];
    const float* bk  = (const float*)d_in[8];
    const float* bv  = (const float*)d_in[9];
    const float* wo  = (const float*)d_in[10];
    const float* bo  = (const float*)d_in[11];
    const float* w1  = (const float*)d_in[12];
    const float* b1  = (const float*)d_in[13];
    const float* w2  = (const float*)d_in[14];
    const float* b2  = (const float*)d_in[15];
    const float* g1  = (const float*)d_in[16];
    const float* be1 = (const float*)d_in[17];
    const float* g2  = (const float*)d_in[18];
    const float* be2 = (const float*)d_in[19];
    const float* g3  = (const float*)d_in[20];
    const float* be3 = (const float*)d_in[21];
    const float* dp  = (const float*)d_in[22];
    const float* db  = (const float*)d_in[23];
    float* out = (float*)d_out;
    ushort_t* ws = (ushort_t*)d_ws;

    // Workspace (bf16 elems). Region A [0, 27,295,744) time-shared:
    //   phase1: xb | mem | kb | vb     phase2 (>= ffn1): ffh (26,214,400)
    ushort_t* xb  = ws;                      // 6272*2048 = 12,845,056
    ushort_t* mem = xb + 12845056;           // 6272*768  =  4,816,896
    ushort_t* kb  = mem + 4816896;
    ushort_t* vb  = kb + 4816896;
    ushort_t* ffh = ws;                      // 12800*2048 = 26,214,400 (phase2)
    ushort_t* rB  = ws + 27295744;
    ushort_t* Wet = rB;                      // 768*2048 = 1,572,864
    ushort_t* wqt = Wet + 1572864;           // 768*768  =   589,824
    ushort_t* wkt = wqt + 589824;            // wkt/wvt adjacent -> fused kv GEMM
    ushort_t* wvt = wkt + 589824;
    ushort_t* wot = wvt + 589824;
    ushort_t* w1t = wot + 589824;            // 2048*768 = 1,572,864
    ushort_t* w2t = w1t + 1572864;           // 768*2048 = 1,572,864
    ushort_t* tgt = w2t + 1572864;           // 100*768 = 76,800
    ushort_t* qb  = tgt + 76800;
    ushort_t* ctx = qb + 76800;              // 12800*768 = 9,830,400
    ushort_t* t2  = ctx + 9830400;
    ushort_t* hb  = t2 + 9830400;

    dim3 blk(256);
    const float qscale = 1.0f / sqrtf((float)HDIM);

    // 0. prep: 7 weight transposes + x convert, one dispatch
    prep_all<<<dim3(2752), blk, 0, stream>>>(We, wq, wk, wv, wo, w1, w2, x,
                                             Wet, wqt, wkt, wvt, wot, w1t, w2t, xb);

    // 1. mem = relu(xb @ We + b_embed)   [6272 x 768, K=2048]  MT=2 -> 588 blocks
    gemm_bf16<2><<<dim3(6, 98), blk, 0, stream>>>(xb, Wet, be_, be_, mem, mem,
                                                  6272, 768, 2048, 768, 1, 1.f, nullptr, 0);
    // 2. tgt = LN(2*qe)                  [100 rows]
    ln4<<<dim3(25), blk, 0, stream>>>(qe, 0, g1, be1, tgt, 2.0f, KQ);
    // 3. qb = (tgt@wq + bq)/sqrt(96)     [100 x 768, K=768]  MT=1 -> 24 blocks
    gemm_bf16<1><<<dim3(6, 4), blk, 0, stream>>>(tgt, wqt, bq, bq, qb, qb,
                                                 KQ, 768, 768, 768, 0, qscale, nullptr, 0);
    // 4. fused k|v                       [6272 x 1536, K=768]  MT=2 -> 1176 blocks
    gemm_bf16<2><<<dim3(12, 98), blk, 0, stream>>>(mem, wkt, bk, bv, kb, vb,
                                                   6272, 1536, 768, 768, 0, 1.f, nullptr, 0);
    // 5. attention -> ctx
    attn_mfma<<<dim3(NB * HEADS), blk, 0, stream>>>(qb, kb, vb, ctx);
    // 6. t2 = ctx@wo + bo + bcast tgt    [12800 x 768, K=768]  MT=2 -> 1200 blocks
    gemm_bf16<2><<<dim3(6, 200), blk, 0, stream>>>(ctx, wot, bo, bo, t2, t2,
                                                   12800, 768, 768, 768, 0, 1.f, tgt, 2);
    // 7. t2 = LN(t2)                     [12800 rows]
    ln4<<<dim3(3200), blk, 0, stream>>>(t2, 1, g2, be2, t2, 1.0f, 12800);
    // 8. ffh = relu(t2@w1 + b1)          [12800 x 2048, K=768]  MT=2 -> 3200 blocks
    gemm_bf16<2><<<dim3(16, 200), blk, 0, stream>>>(t2, w1t, b1, b1, ffh, ffh,
                                                    12800, 2048, 768, 2048, 1, 1.f, nullptr, 0);
    // 9. hb = ffh@w2 + b2 + t2           [12800 x 768, K=2048]  MT=2 -> 1200 blocks
    gemm_bf16<2><<<dim3(6, 200), blk, 0, stream>>>(ffh, w2t, b2, b2, hb, hb,
                                                   12800, 768, 2048, 768, 0, 1.f, t2, 1);
    // 10. GroupFC with fused LN3 -> out (fp32 logits)
    groupfc3<<<dim3(16, KQ), blk, 0, stream>>>(hb, dp, db, g3, be3, out);
}